// Round 10
// baseline (186.626 us; speedup 1.0000x reference)
//
#include <hip/hip_runtime.h>
#include <hip/hip_bf16.h>

#define EPSF 1e-8f

typedef __attribute__((ext_vector_type(8))) short short8;
typedef __attribute__((ext_vector_type(4))) float floatx4;
typedef __attribute__((ext_vector_type(2))) float floatx2;
typedef __attribute__((ext_vector_type(2))) long longx2;

__device__ inline unsigned short f2bf(float v) {
    union { float f; unsigned int u; } un; un.f = v;
    unsigned int r = (un.u + 0x7fffu + ((un.u >> 16) & 1u)) >> 16;
    return (unsigned short)r;
}
__device__ inline float bf2f(unsigned short u) {
    union { unsigned int i; float f; } un; un.i = ((unsigned int)u) << 16;
    return un.f;
}

// ---- fp8 e4m3 (OCP) helpers: HW cvt on gfx950, SW fallback otherwise ----
__device__ inline unsigned char f2fp8(float v) {
#if __has_builtin(__builtin_amdgcn_cvt_pk_fp8_f32)
    return (unsigned char)(__builtin_amdgcn_cvt_pk_fp8_f32(v, 0.f, 0u, false) & 0xff);
#else
    union { float f; unsigned u; } x; x.f = v;
    unsigned s = x.u >> 31; x.u &= 0x7fffffffu;
    if (x.f != x.f || x.f == 0.f) return (unsigned char)(s << 7);
    int e = (int)((x.u >> 23) & 0xff) - 127 + 7;
    unsigned m = x.u & 0x7fffffu;
    unsigned char r;
    if (e >= 1) {
        unsigned keep = m >> 20, rest = m & 0xfffffu;
        keep += (rest > 0x80000u) || (rest == 0x80000u && (keep & 1));
        if (keep == 8) { keep = 0; e += 1; }
        if (e > 15) { e = 15; keep = 6; }
        r = (unsigned char)((e << 3) | keep);
    } else {
        int q = (int)(x.f * 512.f + 0.5f);
        if (q > 7) r = 0x08; else r = (unsigned char)q;
    }
    return (unsigned char)(r | (s << 7));
#endif
}
__device__ inline unsigned pk_fp8x4(float v0, float v1, float v2, float v3) {
#if __has_builtin(__builtin_amdgcn_cvt_pk_fp8_f32)
    unsigned u = __builtin_amdgcn_cvt_pk_fp8_f32(v0, v1, 0u, false);
    u = __builtin_amdgcn_cvt_pk_fp8_f32(v2, v3, u, true);
    return u;
#else
    return (unsigned)f2fp8(v0) | ((unsigned)f2fp8(v1) << 8)
         | ((unsigned)f2fp8(v2) << 16) | ((unsigned)f2fp8(v3) << 24);
#endif
}
__device__ inline floatx2 fp8x2_to_f32(unsigned int u, bool word) {
#if __has_builtin(__builtin_amdgcn_cvt_pk_f32_fp8)
    return word ? __builtin_amdgcn_cvt_pk_f32_fp8(u, true)
                : __builtin_amdgcn_cvt_pk_f32_fp8(u, false);
#else
    floatx2 out;
    #pragma unroll
    for (int i = 0; i < 2; ++i) {
        unsigned char b = (u >> ((word ? 16 : 0) + 8 * i)) & 0xff;
        unsigned s = (b >> 7) & 1, e = (b >> 3) & 15, m = b & 7;
        float v;
        if (e) { union { unsigned u2; float f; } x; x.u2 = (s << 31) | ((e + 120u) << 23) | (m << 20); v = x.f; }
        else   { v = (s ? -1.f : 1.f) * (float)m * 0.001953125f; }
        out[i] = v;
    }
    return out;
#endif
}

// --- K_FRONT: W->fp8 frag-swizzled (blocks [0,32), 16384 u32 PER MATRIX)
//              + xh=|h| (XB blocks) + row histogram (128 blocks). ---
__global__ __launch_bounds__(512) void k_front(
        const float* __restrict__ x, const float* __restrict__ Ws,
        const float* __restrict__ Wn, const int* __restrict__ ei,
        unsigned char* __restrict__ Wswz,
        float* __restrict__ xh, int* __restrict__ hist, int N, int E, int XB) {
    int b = blockIdx.x, t = threadIdx.x;
    if (b < 32) {
        int idx = b * 512 + t;                 // [0, 16384) per-mat u32 index
        int t0 = (idx & 3) * 4;                // byte offset in 16B unit
        int lane = (idx >> 2) & 63;
        int p = (idx >> 8) & 3;
        int g = (idx >> 10) & 3;
        int wq = (idx >> 12) & 3;
        int q = lane >> 4, l16 = lane & 15;
        int row = wq * 64 + g * 16 + l16;
        int s = 2 * p + (t0 >> 3);
        int k0 = 32 * s + 8 * q + (t0 & 7);
        float4 vs = *reinterpret_cast<const float4*>(Ws + row * 256 + k0);
        float4 vn = *reinterpret_cast<const float4*>(Wn + row * 256 + k0);
        reinterpret_cast<unsigned*>(Wswz)[idx] = pk_fp8x4(vs.x, vs.y, vs.z, vs.w);
        reinterpret_cast<unsigned*>(Wswz)[16384 + idx] = pk_fp8x4(vn.x, vn.y, vn.z, vn.w);
    } else if (b < 32 + XB) {
        int i = (b - 32) * 512 + t;
        if (i < N) xh[i] = fabsf(x[(size_t)i * 257 + 256]);
    } else {
        for (int e = (b - 32 - XB) * 512 + t; e < E; e += 128 * 512)
            atomicAdd(&hist[ei[e]], 1);
    }
}

// --- S2: exclusive prefix sum (single block, wave-shfl scan, 1 barrier) ---
__global__ __launch_bounds__(1024) void k_scan(const int* __restrict__ hist,
        int* __restrict__ offs, int* __restrict__ cursor, int N) {
    __shared__ int wtot[16];
    int t = threadIdx.x, lane = t & 63, wv = t >> 6;
    int C = (N + 1023) >> 10;
    int base = t * C;
    int vals[32];
    int s = 0;
    #pragma unroll
    for (int i = 0; i < 32; ++i) {
        if (i < C) {
            int idx = base + i;
            vals[i] = (idx < N) ? hist[idx] : 0;
            s += vals[i];
        }
    }
    int incl = s;
    #pragma unroll
    for (int o = 1; o < 64; o <<= 1) {
        int v = __shfl_up(incl, o, 64);
        if (lane >= o) incl += v;
    }
    if (lane == 63) wtot[wv] = incl;
    __syncthreads();
    int wbase = 0;
    for (int w = 0; w < wv; ++w) wbase += wtot[w];
    int run = wbase + incl - s;
    #pragma unroll
    for (int i = 0; i < 32; ++i) {
        if (i < C) {
            int idx = base + i;
            if (idx < N) { offs[idx] = run; cursor[idx] = run; run += vals[i]; }
        }
    }
}

// --- K_MID: blocks [0,EB): CSR bucket + aggh atomics (FIRST, so their
//            latency chains overlap the GEMM phase);
//            blocks [EB,EB+GB): fp8 double-GEMM + row-normalize, 32 rows,
//            LDS-tiled epilogue for fully-coalesced 16B stores. ---
__global__ __launch_bounds__(512, 4) void k_mid(
        const float* __restrict__ x,
        const unsigned char* __restrict__ Wswz,
        const int* __restrict__ ei, const float* __restrict__ xh,
        int* __restrict__ cursor, int* __restrict__ scol,
        float* __restrict__ aggh,
        unsigned short* __restrict__ selfb, unsigned char* __restrict__ yb8,
        int N, int E, int EB) {
    __shared__ __align__(16) unsigned char As[32][256];       // 8 KB k-staging
    __shared__ __align__(16) unsigned short selfT[32][256];   // 16 KB out tile
    __shared__ __align__(16) unsigned char neighT[32][256];   // 8 KB out tile
    __shared__ float pss[8][32];
    __shared__ float sgnS[32];
    int b = blockIdx.x, tid = threadIdx.x;

    if (b < EB) {                              // ---- bucket part ----
        int e = b * 512 + tid;
        if (e < E) {
            int r = ei[e], c = ei[E + e];
            int pos = atomicAdd(&cursor[r], 1);
            scol[pos] = c;
            atomicAdd(&aggh[r], xh[c]);
        }
        return;
    }

    // ---- GEMM part ----
    int wave = tid >> 6, lane = tid & 63;
    int quad = lane >> 4, l16 = lane & 15;
    int mat = wave >> 2, wq = wave & 3;
    int row0 = (b - EB) * 32;

    if (tid < 32) {
        int gr = row0 + tid; if (gr >= N) gr = N - 1;
        float h = x[(size_t)gr * 257 + 256];
        sgnS[tid] = (h < 0.f) ? -1.f : 1.f;    // sign(0) -> 1 per reference
    }
    __syncthreads();

    // stage A: 32 rows x 256 fp8, k-pair layout + per-row 16B rotation
    #pragma unroll
    for (int ps = 0; ps < 4; ++ps) {
        int c = ps * 512 + tid;
        int row = c >> 6, k0 = (c & 63) * 4;
        int gr = row0 + row; if (gr >= N) gr = N - 1;
        float4 v = *reinterpret_cast<const float4*>(x + (size_t)gr * 257 + k0);
        float sg = sgnS[row];
        int s = k0 >> 5, q = (k0 >> 3) & 3, j0 = k0 & 7;
        int dst = (q * 64 + (s >> 1) * 16 + (s & 1) * 8 + j0 + row * 16) & 255;
        *reinterpret_cast<unsigned*>(&As[row][dst]) =
            pk_fp8x4(v.x * sg, v.y * sg, v.z * sg, v.w * sg);
    }
    __syncthreads();

    const unsigned char* Wb = Wswz + ((size_t)mat << 16) + ((size_t)wq << 14);
    int rowA = l16, rowB = 16 + l16;

    floatx4 acc[2][4];                         // [row-tile][col-group]
    #pragma unroll
    for (int rt = 0; rt < 2; ++rt)
        #pragma unroll
        for (int g = 0; g < 4; ++g) acc[rt][g] = floatx4{0.f, 0.f, 0.f, 0.f};

    #pragma unroll
    for (int p = 0; p < 4; ++p) {              // k-pair: k-steps 2p, 2p+1
        longx2 a0 = *reinterpret_cast<const longx2*>(
            &As[rowA][(quad * 64 + p * 16 + rowA * 16) & 255]);
        longx2 a1 = *reinterpret_cast<const longx2*>(
            &As[rowB][(quad * 64 + p * 16 + rowB * 16) & 255]);
        #pragma unroll
        for (int g = 0; g < 4; ++g) {
            longx2 w = *reinterpret_cast<const longx2*>(
                Wb + (((g * 4 + p) * 64 + lane) << 4));
            acc[0][g] = __builtin_amdgcn_mfma_f32_16x16x32_fp8_fp8(a0[0], w[0], acc[0][g], 0, 0, 0);
            acc[1][g] = __builtin_amdgcn_mfma_f32_16x16x32_fp8_fp8(a1[0], w[0], acc[1][g], 0, 0, 0);
            acc[0][g] = __builtin_amdgcn_mfma_f32_16x16x32_fp8_fp8(a0[1], w[1], acc[0][g], 0, 0, 0);
            acc[1][g] = __builtin_amdgcn_mfma_f32_16x16x32_fp8_fp8(a1[1], w[1], acc[1][g], 0, 0, 0);
        }
    }

    // per-wave row ss partials (C/D: col=16g+l16 (+64wq), row=quad*4+reg)
    #pragma unroll
    for (int rt = 0; rt < 2; ++rt) {
        float s[4];
        #pragma unroll
        for (int reg = 0; reg < 4; ++reg) {
            float v = 0.f;
            #pragma unroll
            for (int g = 0; g < 4; ++g) v += acc[rt][g][reg] * acc[rt][g][reg];
            #pragma unroll
            for (int o = 8; o > 0; o >>= 1) v += __shfl_down(v, o, 64);
            s[reg] = v;
        }
        if (l16 == 0) {
            #pragma unroll
            for (int reg = 0; reg < 4; ++reg)
                pss[wave][rt * 16 + quad * 4 + reg] = s[reg];
        }
    }
    __syncthreads();

    // scale + convert into LDS tiles (scattered writes hit LDS, not L2)
    int wb = mat * 4;
    #pragma unroll
    for (int rt = 0; rt < 2; ++rt)
        #pragma unroll
        for (int reg = 0; reg < 4; ++reg) {
            int r32 = rt * 16 + quad * 4 + reg;
            float ss = pss[wb][r32] + pss[wb + 1][r32]
                     + pss[wb + 2][r32] + pss[wb + 3][r32];
            bool zero = (ss == 0.f);
            float scale = zero ? 0.f : (1.f / fmaxf(sqrtf(ss), EPSF));
            #pragma unroll
            for (int g = 0; g < 4; ++g) {
                int col = wq * 64 + 16 * g + l16;
                float val = zero ? 0.0625f : acc[rt][g][reg] * scale;
                if (mat == 0) selfT[r32][col] = f2bf(val);
                else          neighT[r32][col] = f2fp8(val);
            }
        }
    __syncthreads();

    // fully-coalesced global stores: thread t owns row t>>4, cols [(t&15)*16, +16)
    {
        int r = tid >> 4, c0 = (tid & 15) * 16;
        int gr = row0 + r;
        if (gr < N) {
            *reinterpret_cast<short8*>(selfb + (size_t)gr * 256 + c0) =
                *reinterpret_cast<const short8*>(&selfT[r][c0]);
            *reinterpret_cast<short8*>(selfb + (size_t)gr * 256 + c0 + 8) =
                *reinterpret_cast<const short8*>(&selfT[r][c0 + 8]);
            *reinterpret_cast<longx2*>(yb8 + (size_t)gr * 256 + c0) =
                *reinterpret_cast<const longx2*>(&neighT[r][c0]);
        }
    }
}

// --- S4: ONE WAVE PER NODE, fp8 gather unrolled x4; wave-local epilogue. ---
__global__ __launch_bounds__(256) void k_agg_combine(
        const int* __restrict__ offs, const int* __restrict__ hist,
        const int* __restrict__ scol, const unsigned char* __restrict__ yb8,
        const float* __restrict__ xh, const float* __restrict__ aggh,
        const unsigned short* __restrict__ selfb,
        float* __restrict__ out, int N) {
    int wid = (blockIdx.x * 256 + threadIdx.x) >> 6;   // global wave = node id
    if (wid >= N) return;
    int lane = threadIdx.x & 63;
    int beg = offs[wid], deg = hist[wid];
    float a0 = 0.f, a1 = 0.f, a2 = 0.f, a3 = 0.f;
    float b0 = 0.f, b1 = 0.f, b2 = 0.f, b3 = 0.f;
    int e = beg, end = beg + deg;
    for (; e + 3 < end; e += 4) {
        int c0 = scol[e], c1 = scol[e + 1], c2 = scol[e + 2], c3 = scol[e + 3];
        unsigned u0 = *reinterpret_cast<const unsigned*>(yb8 + (size_t)c0 * 256 + lane * 4);
        unsigned u1 = *reinterpret_cast<const unsigned*>(yb8 + (size_t)c1 * 256 + lane * 4);
        unsigned u2 = *reinterpret_cast<const unsigned*>(yb8 + (size_t)c2 * 256 + lane * 4);
        unsigned u3 = *reinterpret_cast<const unsigned*>(yb8 + (size_t)c3 * 256 + lane * 4);
        floatx2 p;
        p = fp8x2_to_f32(u0, false); a0 += p[0]; a1 += p[1];
        p = fp8x2_to_f32(u0, true);  a2 += p[0]; a3 += p[1];
        p = fp8x2_to_f32(u1, false); b0 += p[0]; b1 += p[1];
        p = fp8x2_to_f32(u1, true);  b2 += p[0]; b3 += p[1];
        p = fp8x2_to_f32(u2, false); a0 += p[0]; a1 += p[1];
        p = fp8x2_to_f32(u2, true);  a2 += p[0]; a3 += p[1];
        p = fp8x2_to_f32(u3, false); b0 += p[0]; b1 += p[1];
        p = fp8x2_to_f32(u3, true);  b2 += p[0]; b3 += p[1];
    }
    for (; e < end; ++e) {
        int c0 = scol[e];
        unsigned u0 = *reinterpret_cast<const unsigned*>(yb8 + (size_t)c0 * 256 + lane * 4);
        floatx2 p;
        p = fp8x2_to_f32(u0, false); a0 += p[0]; a1 += p[1];
        p = fp8x2_to_f32(u0, true);  a2 += p[0]; a3 += p[1];
    }
    a0 += b0; a1 += b1; a2 += b2; a3 += b3;

    float cn = (deg > 0) ? (float)deg : 1.f;
    float m0 = a0 / cn, m1 = a1 / cn, m2 = a2 / cn, m3 = a3 / cn;
    float ss = m0 * m0 + m1 * m1 + m2 * m2 + m3 * m3;
    #pragma unroll
    for (int o = 32; o > 0; o >>= 1) ss += __shfl_xor(ss, o, 64);
    bool z = (ss == 0.f);                      // no-in-edge node: zero_mask -> ones
    float inv = 1.f / fmaxf(z ? 16.f : sqrtf(ss), EPSF);
    float o0 = (z ? 1.f : m0) * inv, o1 = (z ? 1.f : m1) * inv;
    float o2 = (z ? 1.f : m2) * inv, o3 = (z ? 1.f : m3) * inv;

    ushort4 s4 = *reinterpret_cast<const ushort4*>(selfb + (size_t)wid * 256 + lane * 4);
    float v0 = 0.5f * (bf2f(s4.x) + o0), v1 = 0.5f * (bf2f(s4.y) + o1);  // t==1.0f
    float v2 = 0.5f * (bf2f(s4.z) + o2), v3 = 0.5f * (bf2f(s4.w) + o3);
    float ss2 = v0 * v0 + v1 * v1 + v2 * v2 + v3 * v3;
    #pragma unroll
    for (int o = 32; o > 0; o >>= 1) ss2 += __shfl_xor(ss2, o, 64);
    bool z2 = (ss2 == 0.f);
    float inv2 = 1.f / fmaxf(z2 ? 16.f : sqrtf(ss2), EPSF);

    float* op = out + (size_t)wid * 257 + lane * 4;
    op[0] = (z2 ? 1.f : v0) * inv2;
    op[1] = (z2 ? 1.f : v1) * inv2;
    op[2] = (z2 ? 1.f : v2) * inv2;
    op[3] = (z2 ? 1.f : v3) * inv2;
    if (lane == 0) out[(size_t)wid * 257 + 256] = 0.5f * (xh[wid] + 1.f + aggh[wid]);
}

extern "C" void kernel_launch(void* const* d_in, const int* in_sizes, int n_in,
                              void* d_out, int out_size, void* d_ws, size_t ws_size,
                              hipStream_t stream) {
    const float* x  = (const float*)d_in[0];
    const float* Ws = (const float*)d_in[1];
    const float* Wn = (const float*)d_in[2];
    const int*   ei = (const int*)d_in[3];
    int N = in_sizes[0] / 257;
    int E = in_sizes[3] / 2;
    float* out = (float*)d_out;

    char* ws = (char*)d_ws;
    size_t off = 0;
    auto alloc = [&](size_t bytes) {
        void* p = ws + off;
        off = (off + bytes + 255) & ~(size_t)255;
        return p;
    };
    unsigned char* Wswz = (unsigned char*)alloc(131072);   // both mats, frag-swizzled
    float* xh    = (float*)alloc((size_t)N * 4);
    unsigned char* yb8 = (unsigned char*)alloc((size_t)N * 256);
    unsigned short* selfb = (unsigned short*)alloc((size_t)N * 256 * 2);
    int* hist   = (int*)alloc((size_t)N * 4);
    float* aggh = (float*)alloc((size_t)N * 4);
    int* offs   = (int*)alloc((size_t)N * 4);
    int* cursor = (int*)alloc((size_t)N * 4);
    int* scol   = (int*)alloc((size_t)E * 4);

    // zero hist..aggh (contiguous region)
    size_t zbytes = (size_t)((char*)aggh + (size_t)N * 4 - (char*)hist);
    hipMemsetAsync(hist, 0, zbytes, stream);

    // W swizzle + xh + histogram
    int XB = (N + 511) / 512;
    hipLaunchKernelGGL(k_front, dim3(32 + XB + 128), dim3(512), 0, stream,
                       x, Ws, Wn, ei, Wswz, xh, hist, N, E, XB);
    // prefix sum
    hipLaunchKernelGGL(k_scan, dim3(1), dim3(1024), 0, stream, hist, offs, cursor, N);
    // fused: CSR bucket (first) || fp8 double-GEMM + row-normalize
    int GB = (N + 31) / 32, EB = (E + 511) / 512;
    hipLaunchKernelGGL(k_mid, dim3(EB + GB), dim3(512), 0, stream,
                       x, Wswz, ei, xh, cursor, scol, aggh, selfb, yb8, N, E, EB);
    // wave-per-node gather-aggregate + combine
    hipLaunchKernelGGL(k_agg_combine, dim3((N + 3) / 4), dim3(256), 0, stream,
                       offs, hist, scol, yb8, xh, aggh, selfb, out, N);
}

// Round 11
// 184.635 us; speedup vs baseline: 1.0108x; 1.0108x over previous
//
#include <hip/hip_runtime.h>
#include <hip/hip_bf16.h>

#define EPSF 1e-8f

typedef __attribute__((ext_vector_type(8))) short short8;
typedef __attribute__((ext_vector_type(4))) float floatx4;
typedef __attribute__((ext_vector_type(2))) float floatx2;
typedef __attribute__((ext_vector_type(2))) long longx2;

__device__ inline unsigned short f2bf(float v) {
    union { float f; unsigned int u; } un; un.f = v;
    unsigned int r = (un.u + 0x7fffu + ((un.u >> 16) & 1u)) >> 16;
    return (unsigned short)r;
}
__device__ inline float bf2f(unsigned short u) {
    union { unsigned int i; float f; } un; un.i = ((unsigned int)u) << 16;
    return un.f;
}

// ---- fp8 e4m3 (OCP) helpers: HW cvt on gfx950, SW fallback otherwise ----
__device__ inline unsigned char f2fp8(float v) {
#if __has_builtin(__builtin_amdgcn_cvt_pk_fp8_f32)
    return (unsigned char)(__builtin_amdgcn_cvt_pk_fp8_f32(v, 0.f, 0u, false) & 0xff);
#else
    union { float f; unsigned u; } x; x.f = v;
    unsigned s = x.u >> 31; x.u &= 0x7fffffffu;
    if (x.f != x.f || x.f == 0.f) return (unsigned char)(s << 7);
    int e = (int)((x.u >> 23) & 0xff) - 127 + 7;
    unsigned m = x.u & 0x7fffffu;
    unsigned char r;
    if (e >= 1) {
        unsigned keep = m >> 20, rest = m & 0xfffffu;
        keep += (rest > 0x80000u) || (rest == 0x80000u && (keep & 1));
        if (keep == 8) { keep = 0; e += 1; }
        if (e > 15) { e = 15; keep = 6; }
        r = (unsigned char)((e << 3) | keep);
    } else {
        int q = (int)(x.f * 512.f + 0.5f);
        if (q > 7) r = 0x08; else r = (unsigned char)q;
    }
    return (unsigned char)(r | (s << 7));
#endif
}
__device__ inline unsigned pk_fp8x4(float v0, float v1, float v2, float v3) {
#if __has_builtin(__builtin_amdgcn_cvt_pk_fp8_f32)
    unsigned u = __builtin_amdgcn_cvt_pk_fp8_f32(v0, v1, 0u, false);
    u = __builtin_amdgcn_cvt_pk_fp8_f32(v2, v3, u, true);
    return u;
#else
    return (unsigned)f2fp8(v0) | ((unsigned)f2fp8(v1) << 8)
         | ((unsigned)f2fp8(v2) << 16) | ((unsigned)f2fp8(v3) << 24);
#endif
}
__device__ inline floatx2 fp8x2_to_f32(unsigned int u, bool word) {
#if __has_builtin(__builtin_amdgcn_cvt_pk_f32_fp8)
    return word ? __builtin_amdgcn_cvt_pk_f32_fp8(u, true)
                : __builtin_amdgcn_cvt_pk_f32_fp8(u, false);
#else
    floatx2 out;
    #pragma unroll
    for (int i = 0; i < 2; ++i) {
        unsigned char b = (u >> ((word ? 16 : 0) + 8 * i)) & 0xff;
        unsigned s = (b >> 7) & 1, e = (b >> 3) & 15, m = b & 7;
        float v;
        if (e) { union { unsigned u2; float f; } x; x.u2 = (s << 31) | ((e + 120u) << 23) | (m << 20); v = x.f; }
        else   { v = (s ? -1.f : 1.f) * (float)m * 0.001953125f; }
        out[i] = v;
    }
    return out;
#endif
}

// --- K_FRONT: W->fp8 frag-swizzled (blocks [0,32), 16384 u32 PER MATRIX)
//              + xh=|h| (XB blocks) + row histogram (128 blocks). ---
__global__ __launch_bounds__(512) void k_front(
        const float* __restrict__ x, const float* __restrict__ Ws,
        const float* __restrict__ Wn, const int* __restrict__ ei,
        unsigned char* __restrict__ Wswz,
        float* __restrict__ xh, int* __restrict__ hist, int N, int E, int XB) {
    int b = blockIdx.x, t = threadIdx.x;
    if (b < 32) {
        int idx = b * 512 + t;                 // [0, 16384) per-mat u32 index
        int t0 = (idx & 3) * 4;                // byte offset in 16B unit
        int lane = (idx >> 2) & 63;
        int p = (idx >> 8) & 3;
        int g = (idx >> 10) & 3;
        int wq = (idx >> 12) & 3;
        int q = lane >> 4, l16 = lane & 15;
        int row = wq * 64 + g * 16 + l16;
        int s = 2 * p + (t0 >> 3);
        int k0 = 32 * s + 8 * q + (t0 & 7);
        float4 vs = *reinterpret_cast<const float4*>(Ws + row * 256 + k0);
        float4 vn = *reinterpret_cast<const float4*>(Wn + row * 256 + k0);
        reinterpret_cast<unsigned*>(Wswz)[idx] = pk_fp8x4(vs.x, vs.y, vs.z, vs.w);
        reinterpret_cast<unsigned*>(Wswz)[16384 + idx] = pk_fp8x4(vn.x, vn.y, vn.z, vn.w);
    } else if (b < 32 + XB) {
        int i = (b - 32) * 512 + t;
        if (i < N) xh[i] = fabsf(x[(size_t)i * 257 + 256]);
    } else {
        for (int e = (b - 32 - XB) * 512 + t; e < E; e += 128 * 512)
            atomicAdd(&hist[ei[e]], 1);
    }
}

// --- S2: exclusive prefix sum (single block, wave-shfl scan, 1 barrier) ---
__global__ __launch_bounds__(1024) void k_scan(const int* __restrict__ hist,
        int* __restrict__ offs, int* __restrict__ cursor, int N) {
    __shared__ int wtot[16];
    int t = threadIdx.x, lane = t & 63, wv = t >> 6;
    int C = (N + 1023) >> 10;
    int base = t * C;
    int vals[32];
    int s = 0;
    #pragma unroll
    for (int i = 0; i < 32; ++i) {
        if (i < C) {
            int idx = base + i;
            vals[i] = (idx < N) ? hist[idx] : 0;
            s += vals[i];
        }
    }
    int incl = s;
    #pragma unroll
    for (int o = 1; o < 64; o <<= 1) {
        int v = __shfl_up(incl, o, 64);
        if (lane >= o) incl += v;
    }
    if (lane == 63) wtot[wv] = incl;
    __syncthreads();
    int wbase = 0;
    for (int w = 0; w < wv; ++w) wbase += wtot[w];
    int run = wbase + incl - s;
    #pragma unroll
    for (int i = 0; i < 32; ++i) {
        if (i < C) {
            int idx = base + i;
            if (idx < N) { offs[idx] = run; cursor[idx] = run; run += vals[i]; }
        }
    }
}

// --- K_MID (round-9 version): blocks [0,GB): fp8 double-GEMM + row-normalize
//     (32 rows/block); blocks [GB,GB+EB): CSR bucket + aggh atomics. ---
__global__ __launch_bounds__(512, 4) void k_mid(
        const float* __restrict__ x,
        const unsigned char* __restrict__ Wswz,
        const int* __restrict__ ei, const float* __restrict__ xh,
        int* __restrict__ cursor, int* __restrict__ scol,
        float* __restrict__ aggh,
        unsigned short* __restrict__ selfb, unsigned char* __restrict__ yb8,
        int N, int E, int GB) {
    __shared__ __align__(16) unsigned char As[32][256];
    __shared__ float pss[8][32];
    __shared__ float sgnS[32];
    int b = blockIdx.x, tid = threadIdx.x;

    if (b >= GB) {                             // ---- bucket part ----
        int e = (b - GB) * 512 + tid;
        if (e < E) {
            int r = ei[e], c = ei[E + e];
            int pos = atomicAdd(&cursor[r], 1);
            scol[pos] = c;
            atomicAdd(&aggh[r], xh[c]);
        }
        return;
    }

    // ---- GEMM part ----
    int wave = tid >> 6, lane = tid & 63;
    int quad = lane >> 4, l16 = lane & 15;
    int mat = wave >> 2, wq = wave & 3;
    int row0 = b * 32;

    if (tid < 32) {
        int gr = row0 + tid; if (gr >= N) gr = N - 1;
        float h = x[(size_t)gr * 257 + 256];
        sgnS[tid] = (h < 0.f) ? -1.f : 1.f;    // sign(0) -> 1 per reference
    }
    __syncthreads();

    // stage A: 32 rows x 256 fp8, k-pair layout + per-row 16B rotation
    #pragma unroll
    for (int ps = 0; ps < 4; ++ps) {
        int c = ps * 512 + tid;
        int row = c >> 6, k0 = (c & 63) * 4;
        int gr = row0 + row; if (gr >= N) gr = N - 1;
        float4 v = *reinterpret_cast<const float4*>(x + (size_t)gr * 257 + k0);
        float sg = sgnS[row];
        int s = k0 >> 5, q = (k0 >> 3) & 3, j0 = k0 & 7;
        int dst = (q * 64 + (s >> 1) * 16 + (s & 1) * 8 + j0 + row * 16) & 255;
        *reinterpret_cast<unsigned*>(&As[row][dst]) =
            pk_fp8x4(v.x * sg, v.y * sg, v.z * sg, v.w * sg);
    }
    __syncthreads();

    const unsigned char* Wb = Wswz + ((size_t)mat << 16) + ((size_t)wq << 14);
    int rowA = l16, rowB = 16 + l16;

    floatx4 acc[2][4];                         // [row-tile][col-group]
    #pragma unroll
    for (int rt = 0; rt < 2; ++rt)
        #pragma unroll
        for (int g = 0; g < 4; ++g) acc[rt][g] = floatx4{0.f, 0.f, 0.f, 0.f};

    #pragma unroll
    for (int p = 0; p < 4; ++p) {              // k-pair: k-steps 2p, 2p+1
        longx2 a0 = *reinterpret_cast<const longx2*>(
            &As[rowA][(quad * 64 + p * 16 + rowA * 16) & 255]);
        longx2 a1 = *reinterpret_cast<const longx2*>(
            &As[rowB][(quad * 64 + p * 16 + rowB * 16) & 255]);
        #pragma unroll
        for (int g = 0; g < 4; ++g) {
            longx2 w = *reinterpret_cast<const longx2*>(
                Wb + (((g * 4 + p) * 64 + lane) << 4));
            acc[0][g] = __builtin_amdgcn_mfma_f32_16x16x32_fp8_fp8(a0[0], w[0], acc[0][g], 0, 0, 0);
            acc[1][g] = __builtin_amdgcn_mfma_f32_16x16x32_fp8_fp8(a1[0], w[0], acc[1][g], 0, 0, 0);
            acc[0][g] = __builtin_amdgcn_mfma_f32_16x16x32_fp8_fp8(a0[1], w[1], acc[0][g], 0, 0, 0);
            acc[1][g] = __builtin_amdgcn_mfma_f32_16x16x32_fp8_fp8(a1[1], w[1], acc[1][g], 0, 0, 0);
        }
    }

    // per-wave row ss partials (C/D: col=16g+l16 (+64wq), row=quad*4+reg)
    #pragma unroll
    for (int rt = 0; rt < 2; ++rt) {
        float s[4];
        #pragma unroll
        for (int reg = 0; reg < 4; ++reg) {
            float v = 0.f;
            #pragma unroll
            for (int g = 0; g < 4; ++g) v += acc[rt][g][reg] * acc[rt][g][reg];
            #pragma unroll
            for (int o = 8; o > 0; o >>= 1) v += __shfl_down(v, o, 64);
            s[reg] = v;
        }
        if (l16 == 0) {
            #pragma unroll
            for (int reg = 0; reg < 4; ++reg)
                pss[wave][rt * 16 + quad * 4 + reg] = s[reg];
        }
    }
    __syncthreads();

    int wb = mat * 4;
    #pragma unroll
    for (int rt = 0; rt < 2; ++rt)
        #pragma unroll
        for (int reg = 0; reg < 4; ++reg) {
            int r32 = rt * 16 + quad * 4 + reg;
            int gr = row0 + r32;
            if (gr >= N) continue;
            float ss = pss[wb][r32] + pss[wb + 1][r32]
                     + pss[wb + 2][r32] + pss[wb + 3][r32];
            bool zero = (ss == 0.f);
            float scale = zero ? 0.f : (1.f / fmaxf(sqrtf(ss), EPSF));
            #pragma unroll
            for (int g = 0; g < 4; ++g) {
                int col = wq * 64 + 16 * g + l16;
                float val = zero ? 0.0625f : acc[rt][g][reg] * scale;
                if (mat == 0) selfb[(size_t)gr * 256 + col] = f2bf(val);
                else          yb8[(size_t)gr * 256 + col] = f2fp8(val);
            }
        }
}

// --- S4 v3: ONE WAVE PER NODE, dwordx4 gather (4 edges/iter in flight).
// Lane l: edge e+(l>>4), cols [(l&15)*16, +16). 4x fewer load requests.
__global__ __launch_bounds__(256) void k_agg_combine(
        const int* __restrict__ offs, const int* __restrict__ hist,
        const int* __restrict__ scol, const unsigned char* __restrict__ yb8,
        const float* __restrict__ xh, const float* __restrict__ aggh,
        const unsigned short* __restrict__ selfb,
        float* __restrict__ out, int N) {
    int wid = (blockIdx.x * 256 + threadIdx.x) >> 6;   // global wave = node id
    if (wid >= N) return;
    int lane = threadIdx.x & 63;
    int sub = lane >> 4, part = lane & 15;
    int beg = offs[wid], deg = hist[wid];
    int end = beg + deg;

    float acc[16];
    #pragma unroll
    for (int j = 0; j < 16; ++j) acc[j] = 0.f;

    for (int e = beg + sub; e < end; e += 4) {
        int c = scol[e];
        uint4 u = *reinterpret_cast<const uint4*>(yb8 + (size_t)c * 256 + part * 16);
        floatx2 p;
        p = fp8x2_to_f32(u.x, false); acc[0]  += p[0]; acc[1]  += p[1];
        p = fp8x2_to_f32(u.x, true);  acc[2]  += p[0]; acc[3]  += p[1];
        p = fp8x2_to_f32(u.y, false); acc[4]  += p[0]; acc[5]  += p[1];
        p = fp8x2_to_f32(u.y, true);  acc[6]  += p[0]; acc[7]  += p[1];
        p = fp8x2_to_f32(u.z, false); acc[8]  += p[0]; acc[9]  += p[1];
        p = fp8x2_to_f32(u.z, true);  acc[10] += p[0]; acc[11] += p[1];
        p = fp8x2_to_f32(u.w, false); acc[12] += p[0]; acc[13] += p[1];
        p = fp8x2_to_f32(u.w, true);  acc[14] += p[0]; acc[15] += p[1];
    }
    // fold the 4 edge-subgroups (lanes l, l^16, l^32, l^48 share cols)
    #pragma unroll
    for (int j = 0; j < 16; ++j) {
        acc[j] += __shfl_xor(acc[j], 16, 64);
        acc[j] += __shfl_xor(acc[j], 32, 64);
    }

    float cn = (deg > 0) ? (float)deg : 1.f;
    float m[16];
    float ss = 0.f;
    #pragma unroll
    for (int j = 0; j < 16; ++j) { m[j] = acc[j] / cn; ss += m[j] * m[j]; }
    #pragma unroll
    for (int o = 8; o > 0; o >>= 1) ss += __shfl_xor(ss, o, 64);
    bool z = (ss == 0.f);                      // no-in-edge node: zero_mask -> ones
    float inv = 1.f / fmaxf(z ? 16.f : sqrtf(ss), EPSF);

    const unsigned short* sp = selfb + (size_t)wid * 256 + part * 16;
    short8 s0 = *reinterpret_cast<const short8*>(sp);
    short8 s1 = *reinterpret_cast<const short8*>(sp + 8);
    float vv[16];
    float ss2 = 0.f;
    #pragma unroll
    for (int j = 0; j < 16; ++j) {
        float oj = (z ? 1.f : m[j]) * inv;
        unsigned short sb = (unsigned short)((j < 8) ? s0[j] : s1[j - 8]);
        vv[j] = 0.5f * (bf2f(sb) + oj);        // t = 0.5/(0.5+1e-8) == 1.0f in fp32
        ss2 += vv[j] * vv[j];
    }
    #pragma unroll
    for (int o = 8; o > 0; o >>= 1) ss2 += __shfl_xor(ss2, o, 64);
    bool z2 = (ss2 == 0.f);
    float inv2 = 1.f / fmaxf(z2 ? 16.f : sqrtf(ss2), EPSF);

    if (sub == 0) {                            // lanes 0-15 store 64 B each
        float* op = out + (size_t)wid * 257 + part * 16;
        #pragma unroll
        for (int j = 0; j < 16; ++j) op[j] = (z2 ? 1.f : vv[j]) * inv2;
    }
    if (lane == 0) out[(size_t)wid * 257 + 256] = 0.5f * (xh[wid] + 1.f + aggh[wid]);
}

extern "C" void kernel_launch(void* const* d_in, const int* in_sizes, int n_in,
                              void* d_out, int out_size, void* d_ws, size_t ws_size,
                              hipStream_t stream) {
    const float* x  = (const float*)d_in[0];
    const float* Ws = (const float*)d_in[1];
    const float* Wn = (const float*)d_in[2];
    const int*   ei = (const int*)d_in[3];
    int N = in_sizes[0] / 257;
    int E = in_sizes[3] / 2;
    float* out = (float*)d_out;

    char* ws = (char*)d_ws;
    size_t off = 0;
    auto alloc = [&](size_t bytes) {
        void* p = ws + off;
        off = (off + bytes + 255) & ~(size_t)255;
        return p;
    };
    unsigned char* Wswz = (unsigned char*)alloc(131072);   // both mats, frag-swizzled
    float* xh    = (float*)alloc((size_t)N * 4);
    unsigned char* yb8 = (unsigned char*)alloc((size_t)N * 256);
    unsigned short* selfb = (unsigned short*)alloc((size_t)N * 256 * 2);
    int* hist   = (int*)alloc((size_t)N * 4);
    float* aggh = (float*)alloc((size_t)N * 4);
    int* offs   = (int*)alloc((size_t)N * 4);
    int* cursor = (int*)alloc((size_t)N * 4);
    int* scol   = (int*)alloc((size_t)E * 4);

    // zero hist..aggh (contiguous region)
    size_t zbytes = (size_t)((char*)aggh + (size_t)N * 4 - (char*)hist);
    hipMemsetAsync(hist, 0, zbytes, stream);

    // W swizzle + xh + histogram
    int XB = (N + 511) / 512;
    hipLaunchKernelGGL(k_front, dim3(32 + XB + 128), dim3(512), 0, stream,
                       x, Ws, Wn, ei, Wswz, xh, hist, N, E, XB);
    // prefix sum
    hipLaunchKernelGGL(k_scan, dim3(1), dim3(1024), 0, stream, hist, offs, cursor, N);
    // fused: fp8 double-GEMM (+row-normalize) || CSR bucket (+aggh)
    int GB = (N + 31) / 32, EB = (E + 511) / 512;
    hipLaunchKernelGGL(k_mid, dim3(GB + EB), dim3(512), 0, stream,
                       x, Wswz, ei, xh, cursor, scol, aggh, selfb, yb8, N, E, GB);
    // wave-per-node gather-aggregate + combine (dwordx4 gather)
    hipLaunchKernelGGL(k_agg_combine, dim3((N + 3) / 4), dim3(256), 0, stream,
                       offs, hist, scol, yb8, xh, aggh, selfb, out, N);
}